// Round 5
// baseline (491.883 us; speedup 1.0000x reference)
//
#include <hip/hip_runtime.h>
#include <hip/hip_bf16.h>

// B=4, L=2048, D=1024, H=16, DH=64.  out = proj( softmax(QK^T/8) V ), fused QKV.
// Inputs fp32 (runtime-detected), compute bf16 MFMA, output dtype follows input.
// R13: base = R2/R10 (283.2 us best). attn LDS-traffic cut WITHOUT occupancy
//      loss (R12 lesson): V staging deleted (PV B-frags read directly from
//      L2-resident vtb; loads hoisted pre-QK so latency hides under QK+softmax);
//      K-only double-buffer (2x64x72) + dedicated wave-private P buffer
//      (4x32x72) keeps LDS at 36864 B -> 4 blocks/CU, 16 waves. Single
//      __syncthreads per K-tile (K[cur] reads vs K[nxt] writes disjoint).
//      XCD-chunked 1D swizzle: all 16 q-blocks of a bh on one XCD so K/V are
//      fetched from HBM once (FETCH_SIZE was 3x ideal). gemm/cvt3 = R2 exact.

typedef __bf16  bf16x8  __attribute__((ext_vector_type(8)));
typedef __bf16  bf16x4  __attribute__((ext_vector_type(4)));
typedef float   floatx4 __attribute__((ext_vector_type(4)));

__device__ __forceinline__ void async_ld16(const void* g, void* lds_base_uniform) {
  __builtin_amdgcn_global_load_lds(
      (const __attribute__((address_space(1))) void*)g,
      (__attribute__((address_space(3))) void*)lds_base_uniform,
      16, 0, 0);
}

// bf16-vs-fp32 probe: even uint16s of bf16 N(0,s) data have sane exponents;
// fp32 low-mantissa halves are uniform.
__device__ __forceinline__ int detect_bf16(const void* p) {
  const unsigned short* u = (const unsigned short*)p;
  int sane = 0;
#pragma unroll 4
  for (int i = 0; i < 64; ++i) {
    unsigned short w = u[2 * i];
    int e = (w >> 7) & 0xFF;
    sane += (w == 0 || (e >= 100 && e <= 150)) ? 1 : 0;
  }
  return sane >= 32;
}

__device__ __forceinline__ bf16x8 ld8_f32cvt(const void* base, size_t elem) {
  const float* p = (const float*)base + elem;
  floatx4 u0 = *(const floatx4*)p;
  floatx4 u1 = *(const floatx4*)(p + 4);
  bf16x8 v;
  v[0] = (__bf16)u0[0]; v[1] = (__bf16)u0[1]; v[2] = (__bf16)u0[2]; v[3] = (__bf16)u0[3];
  v[4] = (__bf16)u1[0]; v[5] = (__bf16)u1[1]; v[6] = (__bf16)u1[2]; v[7] = (__bf16)u1[3];
  return v;
}

// DPP cross-lane sum within 16-lane rows (verified R4-R7).
template<int CTRL>
__device__ __forceinline__ float dpp_f(float x) {
  return __builtin_bit_cast(float,
      __builtin_amdgcn_update_dpp(0, __builtin_bit_cast(int, x), CTRL, 0xF, 0xF, true));
}
__device__ __forceinline__ float row16_sum(float x) {
  x += dpp_f<0xB1>(x);
  x += dpp_f<0x4E>(x);
  x += dpp_f<0x141>(x);
  x += dpp_f<0x140>(x);
  return x;
}

// ---------------------------------------------------------------------------
// fused dtype-normalizing copy over 3 segments (segment starts block-aligned)
// ---------------------------------------------------------------------------
__launch_bounds__(256)
__global__ void cvt3_kernel(const void* __restrict__ s0, __bf16* __restrict__ d0, int n0,
                            const void* __restrict__ s1, __bf16* __restrict__ d1, int n1,
                            const void* __restrict__ s2, __bf16* __restrict__ d2) {
  int u = blockIdx.x * blockDim.x + threadIdx.x;
  const void* src; __bf16* dst;
  if (u < n0)           { src = s0; dst = d0; }
  else if (u < n0 + n1) { src = s1; dst = d1; u -= n0; }
  else                  { src = s2; dst = d2; u -= n0 + n1; }
  const int is_bf16 = detect_bf16(src);
  const size_t e = (size_t)u * 8;
  if (is_bf16) *(bf16x8*)(dst + e) = *(const bf16x8*)((const __bf16*)src + e);
  else         *(bf16x8*)(dst + e) = ld8_f32cvt(src, e);
}

// ---------------------------------------------------------------------------
// gemm_bt: C[M,N] = A[M,K] * B[N,K]^T  (m97: 128x128 tile, BK=32, async staging)
// XCD-local decode: xcd = flat&7 owns an 8-m-tile slab (2MB, L2-resident).
// EPI 0: scatter to Q/K [BH,L,DH] and VT [BH,DH,L] (V packed b64 along l).
// EPI 1: row-major store, dtype per runtime probe of `oprobe`.
// ---------------------------------------------------------------------------
template<int EPI>
__launch_bounds__(256, 2)
__global__ void gemm_bt_kernel(const __bf16* __restrict__ A,
                               const __bf16* __restrict__ B,
                               const void* __restrict__ oprobe,
                               void* __restrict__ Cout,
                               __bf16* __restrict__ qb,
                               __bf16* __restrict__ kb,
                               __bf16* __restrict__ vtb,
                               int M, int N, int K)
{
  __shared__ __align__(16) __bf16 As[128 * 32];
  __shared__ __align__(16) __bf16 Bs[128 * 32];

  const int flat = blockIdx.x;
  const int m0 = (((flat & 7) << 3) | ((flat >> 3) & 7)) << 7;
  const int n0 = (flat >> 6) << 7;

  const int tid  = threadIdx.x;
  const int wave = tid >> 6;
  const int lane = tid & 63;
  const int quad = lane >> 4;
  const int l16  = lane & 15;
  const int wm   = wave >> 1;
  const int wn   = wave & 1;

  const int r_in   = lane >> 2;
  const int cchunk = lane & 3;

  const __bf16* Ab = A + (size_t)m0 * K;
  const __bf16* Bb = B + (size_t)n0 * K;

  floatx4 acc[4][4];
#pragma unroll
  for (int i = 0; i < 4; ++i)
#pragma unroll
    for (int j = 0; j < 4; ++j)
      acc[i][j] = (floatx4){0.f, 0.f, 0.f, 0.f};

  const int ca0 = wave * 2;
  for (int k0 = 0; k0 < K; k0 += 32) {
#pragma unroll
    for (int i = 0; i < 2; ++i) {
      const int ca  = ca0 + i;
      const int row = ca * 16 + r_in;
      async_ld16(Ab + (size_t)row * K + k0 + cchunk * 8, (char*)As + ca * 1024);
      async_ld16(Bb + (size_t)row * K + k0 + cchunk * 8, (char*)Bs + ca * 1024);
    }
    __syncthreads();

    bf16x8 af[4], bfr[4];
#pragma unroll
    for (int tt = 0; tt < 4; ++tt) {
      af[tt]  = *(const bf16x8*)&As[(wm * 64 + tt * 16 + l16) * 32 + quad * 8];
      bfr[tt] = *(const bf16x8*)&Bs[(wn * 64 + tt * 16 + l16) * 32 + quad * 8];
    }
#pragma unroll
    for (int mt = 0; mt < 4; ++mt)
#pragma unroll
      for (int nt = 0; nt < 4; ++nt)
        acc[mt][nt] = __builtin_amdgcn_mfma_f32_16x16x32_bf16(af[mt], bfr[nt], acc[mt][nt], 0, 0, 0);
    __syncthreads();
  }

  const int out_bf16 = (EPI == 1) ? detect_bf16(oprobe) : 0;

  // C/D layout: col = lane&15, row = quad*4 + reg
#pragma unroll
  for (int mt = 0; mt < 4; ++mt) {
#pragma unroll
    for (int nt = 0; nt < 4; ++nt) {
      const int n_idx = n0 + wn * 64 + nt * 16 + l16;
      const int mbase = m0 + wm * 64 + mt * 16 + quad * 4;
      if (EPI == 1) {
        if (out_bf16) {
#pragma unroll
          for (int r = 0; r < 4; ++r)
            ((__bf16*)Cout)[(size_t)(mbase + r) * N + n_idx] = (__bf16)acc[mt][nt][r];
        } else {
#pragma unroll
          for (int r = 0; r < 4; ++r)
            ((float*)Cout)[(size_t)(mbase + r) * N + n_idx] = acc[mt][nt][r];
        }
      } else {
        const int sel = n_idx >> 10;        // 0=Q 1=K 2=V (uniform per block)
        const int rem = n_idx & 1023;
        const int h   = rem >> 6;
        const int dh  = rem & 63;
        const int b   = mbase >> 11;        // same for r=0..3 (mbase % 4 == 0)
        const int l   = mbase & 2047;
        const int bh  = b * 16 + h;
        if (sel == 2) {
          bf16x4 pk;
#pragma unroll
          for (int r = 0; r < 4; ++r) pk[r] = (__bf16)acc[mt][nt][r];
          *(bf16x4*)&vtb[((size_t)bh * 64 + dh) * 2048 + l] = pk;   // 4 consecutive l
        } else {
          __bf16* dstb = (sel == 0 ? qb : kb) + ((size_t)bh * 2048 + l) * 64 + dh;
#pragma unroll
          for (int r = 0; r < 4; ++r)
            dstb[(size_t)r * 64] = (__bf16)acc[mt][nt][r];
        }
      }
    }
  }
}

// ---------------------------------------------------------------------------
// Flash attention: 1D grid 1024 blocks (XCD-chunked swizzle: all 16 q-blocks
// of a bh on one XCD => K/V L2-local, fetched from HBM once). 4 waves/block,
// 32 Q rows per wave. Fixed-shift softmax p = exp(s/8 - 8); l via ones-column
// (register B-frag). S^T = K Q^T (x32 MFMA); P round-trips through a dedicated
// wave-private LDS quarter. V is NOT staged: PV B-frags are direct 16B global
// reads from L2-resident vtb, hoisted before QK so latency hides under
// compute. K-only double-buffer via register prefetch; K[cur] reads and
// K[nxt] writes are disjoint => ONE __syncthreads per K-tile.
// ---------------------------------------------------------------------------
__launch_bounds__(256, 4)
__global__ void attn_kernel(const __bf16* __restrict__ qb,
                            const __bf16* __restrict__ kb,
                            const __bf16* __restrict__ vtb,
                            __bf16* __restrict__ ob /* [B,L,D] bf16 */)
{
  __shared__ __align__(16) __bf16 Ks[2][64 * 72];
  __shared__ __align__(16) __bf16 Ps[4][32 * 72];

  const int tid  = threadIdx.x;
  const int wave = tid >> 6;
  const int lane = tid & 63;
  const int quad = lane >> 4;
  const int l16  = lane & 15;

  // XCD-chunked bijective swizzle (1024 % 8 == 0): xcd c owns bh [8c, 8c+8)
  const int flat = blockIdx.x;
  const int swz  = (flat & 7) * 128 + (flat >> 3);
  const int bh   = swz >> 4;
  const int q0   = (swz & 15) * 128;
  const int b    = bh >> 4;
  const int h    = bh & 15;

  const __bf16* Qp = qb  + (size_t)bh * 2048 * 64;
  const __bf16* Kp = kb  + (size_t)bh * 2048 * 64;
  const __bf16* Vp = vtb + (size_t)bh * 64 * 2048;

  const float C1 = 0.125f * 1.44269504f;
  const float C2 = -8.0f  * 1.44269504f;

  bf16x8 aq[2][2];
#pragma unroll
  for (int rt = 0; rt < 2; ++rt) {
    const __bf16* qrow = Qp + (size_t)(q0 + wave * 32 + rt * 16 + l16) * 64;
    aq[rt][0] = *(const bf16x8*)(qrow + quad * 8);
    aq[rt][1] = *(const bf16x8*)(qrow + 32 + quad * 8);
  }

  // ones column, x32 B-frag: B[k=quad*8+e][n=l16] = 1 at n==0
  bf16x8 onesb;
  {
    const __bf16 ov = (l16 == 0) ? (__bf16)1.0f : (__bf16)0.0f;
#pragma unroll
    for (int i = 0; i < 8; ++i) onesb[i] = ov;
  }

  floatx4 o[2][4], o5[2];
#pragma unroll
  for (int rt = 0; rt < 2; ++rt) {
    o5[rt] = (floatx4){0.f, 0.f, 0.f, 0.f};
#pragma unroll
    for (int dt = 0; dt < 4; ++dt) o[rt][dt] = (floatx4){0.f, 0.f, 0.f, 0.f};
  }

  // K staging: cooperative 256 threads, 2 b128 each: rows (tid>>3)+{0,32},
  // col (tid&7)*8. K tile = 64 rows x 64 cols.
  const int sr0  = tid >> 3;          // 0..31
  const int scol = (tid & 7) * 8;

  // prologue: stage K tile 0
#pragma unroll
  for (int i = 0; i < 2; ++i) {
    const int row = sr0 + 32 * i;
    *(bf16x8*)&Ks[0][row * 72 + scol] = *(const bf16x8*)(Kp + (size_t)row * 64 + scol);
  }
  __syncthreads();

  for (int kt = 0; kt < 32; ++kt) {
    const int cur = kt & 1;
    const int nxt = cur ^ 1;
    const int kn  = (((kt + 1) & 31) << 6);

    // issue next K tile's global loads now; LDS-written after compute
    bf16x8 kreg[2];
#pragma unroll
    for (int i = 0; i < 2; ++i) {
      const int row = sr0 + 32 * i;
      kreg[i] = *(const bf16x8*)(Kp + (size_t)(kn + row) * 64 + scol);
    }

    // V B-frags for this tile: direct global (L2-local via swizzle), hoisted
    // here so ~200cy L2 latency hides under QK + softmax.
    bf16x8 vb[4][2];
#pragma unroll
    for (int dt = 0; dt < 4; ++dt) {
      const __bf16* vr = Vp + (size_t)(dt * 16 + l16) * 2048 + (kt << 6);
      vb[dt][0] = *(const bf16x8*)(vr + quad * 8);
      vb[dt][1] = *(const bf16x8*)(vr + 32 + quad * 8);
    }

    const __bf16* Kc = &Ks[cur][0];
    __bf16*       Pq = &Ps[wave][0];

    // S^T = K Q^T (row=key, col=q): A=K-frags, B=Q-frags
    floatx4 st[2][4];
    __builtin_amdgcn_s_setprio(1);
#pragma unroll
    for (int nt = 0; nt < 4; ++nt) {
      const int krow = nt * 16 + l16;
      bf16x8 ak0 = *(const bf16x8*)&Kc[krow * 72 + quad * 8];
      bf16x8 ak1 = *(const bf16x8*)&Kc[krow * 72 + 32 + quad * 8];
#pragma unroll
      for (int rt = 0; rt < 2; ++rt) {
        floatx4 z = (floatx4){0.f, 0.f, 0.f, 0.f};
        z = __builtin_amdgcn_mfma_f32_16x16x32_bf16(ak0, aq[rt][0], z, 0, 0, 0);
        z = __builtin_amdgcn_mfma_f32_16x16x32_bf16(ak1, aq[rt][1], z, 0, 0, 0);
        st[rt][nt] = z;
      }
    }
    __builtin_amdgcn_s_setprio(0);

    // softmax + packed P write: lane holds keys nt*16+quad*4+{0..3} of q-row l16
#pragma unroll
    for (int rt = 0; rt < 2; ++rt) {
#pragma unroll
      for (int nt = 0; nt < 4; ++nt) {
        bf16x4 pk;
#pragma unroll
        for (int r = 0; r < 4; ++r)
          pk[r] = (__bf16)__builtin_amdgcn_exp2f(fmaf(st[rt][nt][r], C1, C2));
        *(bf16x4*)&Pq[(rt * 16 + l16) * 72 + nt * 16 + quad * 4] = pk;
      }
    }

    __builtin_amdgcn_wave_barrier();   // pin LDS write->read order (same wave)

    bf16x8 ap[2][2];
#pragma unroll
    for (int rt = 0; rt < 2; ++rt) {
      ap[rt][0] = *(const bf16x8*)&Pq[(rt * 16 + l16) * 72 + quad * 8];
      ap[rt][1] = *(const bf16x8*)&Pq[(rt * 16 + l16) * 72 + 32 + quad * 8];
    }

    __builtin_amdgcn_s_setprio(1);
#pragma unroll
    for (int dt = 0; dt < 4; ++dt) {
#pragma unroll
      for (int rt = 0; rt < 2; ++rt) {
        o[rt][dt] = __builtin_amdgcn_mfma_f32_16x16x32_bf16(ap[rt][0], vb[dt][0], o[rt][dt], 0, 0, 0);
        o[rt][dt] = __builtin_amdgcn_mfma_f32_16x16x32_bf16(ap[rt][1], vb[dt][1], o[rt][dt], 0, 0, 0);
      }
    }
    // ones-column: l accumulates in col 0 of o5
#pragma unroll
    for (int rt = 0; rt < 2; ++rt) {
      o5[rt] = __builtin_amdgcn_mfma_f32_16x16x32_bf16(ap[rt][0], onesb, o5[rt], 0, 0, 0);
      o5[rt] = __builtin_amdgcn_mfma_f32_16x16x32_bf16(ap[rt][1], onesb, o5[rt], 0, 0, 0);
    }
    __builtin_amdgcn_s_setprio(0);

    // stage K tile kt+1 into Ks[nxt] (disjoint from Ks[cur] reads)
#pragma unroll
    for (int i = 0; i < 2; ++i) {
      const int row = sr0 + 32 * i;
      *(bf16x8*)&Ks[nxt][row * 72 + scol] = kreg[i];
    }
    __syncthreads();   // next K tile ready for all waves
  }

#pragma unroll
  for (int rt = 0; rt < 2; ++rt)
#pragma unroll
    for (int r = 0; r < 4; ++r) {
      const float lv  = row16_sum(l16 == 0 ? o5[rt][r] : 0.f);
      const float inv = 1.f / lv;
      const size_t rowbase =
          ((size_t)b * 2048 + q0 + wave * 32 + rt * 16 + quad * 4 + r) * 1024 + h * 64;
#pragma unroll
      for (int dt = 0; dt < 4; ++dt)
        ob[rowbase + dt * 16 + l16] = (__bf16)(o[rt][dt][r] * inv);
    }
}

// ---------------------------------------------------------------------------
extern "C" void kernel_launch(void* const* d_in, const int* in_sizes, int n_in,
                              void* d_out, int out_size, void* d_ws, size_t ws_size,
                              hipStream_t stream)
{
  (void)in_sizes; (void)n_in; (void)out_size; (void)ws_size;

  const void* x     = d_in[0];
  const void* wqkv  = d_in[1];
  const void* wproj = d_in[2];

  const size_t NX    = (size_t)8192 * 1024;
  const size_t NWQKV = (size_t)3072 * 1024;
  const size_t NWPRJ = (size_t)1024 * 1024;

  __bf16* qbuf   = (__bf16*)d_ws;
  __bf16* kbuf   = qbuf + NX;
  __bf16* vtbuf  = kbuf + NX;
  __bf16* abuf   = vtbuf + NX;
  __bf16* xb     = abuf + NX;
  __bf16* wqkvb  = xb + NX;
  __bf16* wprojb = wqkvb + NWQKV;

  dim3 blk(256);

  cvt3_kernel<<<dim3((NX + NWQKV + NWPRJ) / 2048), blk, 0, stream>>>(
      x, xb, NX / 8, wqkv, wqkvb, NWQKV / 8, wproj, wprojb);

  gemm_bt_kernel<0><<<dim3(24 * 64), blk, 0, stream>>>(
      xb, wqkvb, nullptr, nullptr, qbuf, kbuf, vtbuf, 8192, 3072, 1024);

  attn_kernel<<<dim3(1024), blk, 0, stream>>>(qbuf, kbuf, vtbuf, abuf);

  gemm_bt_kernel<1><<<dim3(8 * 64), blk, 0, stream>>>(
      abuf, wprojb, wproj, d_out, nullptr, nullptr, nullptr, 8192, 1024, 1024);
}

// Round 6
// 288.087 us; speedup vs baseline: 1.7074x; 1.7074x over previous
//
#include <hip/hip_runtime.h>
#include <hip/hip_bf16.h>

// B=4, L=2048, D=1024, H=16, DH=64.  out = proj( softmax(QK^T/8) V ), fused QKV.
// Inputs fp32 (runtime-detected), compute bf16 MFMA, output dtype follows input.
// R14: attn = R10-exact revert (283.2us config; R11/R12/R13 all regressed it —
//      R13 post-mortem: flat&7->XCD mapping falsified, direct-V reads thrashed
//      L2 at 500MB HBM fetch). One variable this round: gemm __launch_bounds__
//      (256,2)->(256,3). m97's 874-912 TF ran at 164 VGPR = 3 waves/SIMD; the
//      (256,2) bound capped us at 8 waves/CU, 33% under the proven config.

typedef __bf16  bf16x8  __attribute__((ext_vector_type(8)));
typedef __bf16  bf16x4  __attribute__((ext_vector_type(4)));
typedef float   floatx4 __attribute__((ext_vector_type(4)));

__device__ __forceinline__ void async_ld16(const void* g, void* lds_base_uniform) {
  __builtin_amdgcn_global_load_lds(
      (const __attribute__((address_space(1))) void*)g,
      (__attribute__((address_space(3))) void*)lds_base_uniform,
      16, 0, 0);
}

// bf16-vs-fp32 probe: even uint16s of bf16 N(0,s) data have sane exponents;
// fp32 low-mantissa halves are uniform.
__device__ __forceinline__ int detect_bf16(const void* p) {
  const unsigned short* u = (const unsigned short*)p;
  int sane = 0;
#pragma unroll 4
  for (int i = 0; i < 64; ++i) {
    unsigned short w = u[2 * i];
    int e = (w >> 7) & 0xFF;
    sane += (w == 0 || (e >= 100 && e <= 150)) ? 1 : 0;
  }
  return sane >= 32;
}

__device__ __forceinline__ bf16x8 ld8_f32cvt(const void* base, size_t elem) {
  const float* p = (const float*)base + elem;
  floatx4 u0 = *(const floatx4*)p;
  floatx4 u1 = *(const floatx4*)(p + 4);
  bf16x8 v;
  v[0] = (__bf16)u0[0]; v[1] = (__bf16)u0[1]; v[2] = (__bf16)u0[2]; v[3] = (__bf16)u0[3];
  v[4] = (__bf16)u1[0]; v[5] = (__bf16)u1[1]; v[6] = (__bf16)u1[2]; v[7] = (__bf16)u1[3];
  return v;
}

// DPP cross-lane sum within 16-lane rows (verified R4-R7).
template<int CTRL>
__device__ __forceinline__ float dpp_f(float x) {
  return __builtin_bit_cast(float,
      __builtin_amdgcn_update_dpp(0, __builtin_bit_cast(int, x), CTRL, 0xF, 0xF, true));
}
__device__ __forceinline__ float row16_sum(float x) {
  x += dpp_f<0xB1>(x);
  x += dpp_f<0x4E>(x);
  x += dpp_f<0x141>(x);
  x += dpp_f<0x140>(x);
  return x;
}

// ---------------------------------------------------------------------------
// fused dtype-normalizing copy over 3 segments (segment starts block-aligned)
// ---------------------------------------------------------------------------
__launch_bounds__(256)
__global__ void cvt3_kernel(const void* __restrict__ s0, __bf16* __restrict__ d0, int n0,
                            const void* __restrict__ s1, __bf16* __restrict__ d1, int n1,
                            const void* __restrict__ s2, __bf16* __restrict__ d2) {
  int u = blockIdx.x * blockDim.x + threadIdx.x;
  const void* src; __bf16* dst;
  if (u < n0)           { src = s0; dst = d0; }
  else if (u < n0 + n1) { src = s1; dst = d1; u -= n0; }
  else                  { src = s2; dst = d2; u -= n0 + n1; }
  const int is_bf16 = detect_bf16(src);
  const size_t e = (size_t)u * 8;
  if (is_bf16) *(bf16x8*)(dst + e) = *(const bf16x8*)((const __bf16*)src + e);
  else         *(bf16x8*)(dst + e) = ld8_f32cvt(src, e);
}

// ---------------------------------------------------------------------------
// gemm_bt: C[M,N] = A[M,K] * B[N,K]^T  (m97: 128x128 tile, BK=32, async staging)
// XCD-local decode: xcd = flat&7 owns an 8-m-tile slab (2MB, L2-resident).
// EPI 0: scatter to Q/K [BH,L,DH] and VT [BH,DH,L] (V packed b64 along l).
// EPI 1: row-major store, dtype per runtime probe of `oprobe`.
// ---------------------------------------------------------------------------
template<int EPI>
__launch_bounds__(256, 3)
__global__ void gemm_bt_kernel(const __bf16* __restrict__ A,
                               const __bf16* __restrict__ B,
                               const void* __restrict__ oprobe,
                               void* __restrict__ Cout,
                               __bf16* __restrict__ qb,
                               __bf16* __restrict__ kb,
                               __bf16* __restrict__ vtb,
                               int M, int N, int K)
{
  __shared__ __align__(16) __bf16 As[128 * 32];
  __shared__ __align__(16) __bf16 Bs[128 * 32];

  const int flat = blockIdx.x;
  const int m0 = (((flat & 7) << 3) | ((flat >> 3) & 7)) << 7;
  const int n0 = (flat >> 6) << 7;

  const int tid  = threadIdx.x;
  const int wave = tid >> 6;
  const int lane = tid & 63;
  const int quad = lane >> 4;
  const int l16  = lane & 15;
  const int wm   = wave >> 1;
  const int wn   = wave & 1;

  const int r_in   = lane >> 2;
  const int cchunk = lane & 3;

  const __bf16* Ab = A + (size_t)m0 * K;
  const __bf16* Bb = B + (size_t)n0 * K;

  floatx4 acc[4][4];
#pragma unroll
  for (int i = 0; i < 4; ++i)
#pragma unroll
    for (int j = 0; j < 4; ++j)
      acc[i][j] = (floatx4){0.f, 0.f, 0.f, 0.f};

  const int ca0 = wave * 2;
  for (int k0 = 0; k0 < K; k0 += 32) {
#pragma unroll
    for (int i = 0; i < 2; ++i) {
      const int ca  = ca0 + i;
      const int row = ca * 16 + r_in;
      async_ld16(Ab + (size_t)row * K + k0 + cchunk * 8, (char*)As + ca * 1024);
      async_ld16(Bb + (size_t)row * K + k0 + cchunk * 8, (char*)Bs + ca * 1024);
    }
    __syncthreads();

    bf16x8 af[4], bfr[4];
#pragma unroll
    for (int tt = 0; tt < 4; ++tt) {
      af[tt]  = *(const bf16x8*)&As[(wm * 64 + tt * 16 + l16) * 32 + quad * 8];
      bfr[tt] = *(const bf16x8*)&Bs[(wn * 64 + tt * 16 + l16) * 32 + quad * 8];
    }
#pragma unroll
    for (int mt = 0; mt < 4; ++mt)
#pragma unroll
      for (int nt = 0; nt < 4; ++nt)
        acc[mt][nt] = __builtin_amdgcn_mfma_f32_16x16x32_bf16(af[mt], bfr[nt], acc[mt][nt], 0, 0, 0);
    __syncthreads();
  }

  const int out_bf16 = (EPI == 1) ? detect_bf16(oprobe) : 0;

  // C/D layout: col = lane&15, row = quad*4 + reg
#pragma unroll
  for (int mt = 0; mt < 4; ++mt) {
#pragma unroll
    for (int nt = 0; nt < 4; ++nt) {
      const int n_idx = n0 + wn * 64 + nt * 16 + l16;
      const int mbase = m0 + wm * 64 + mt * 16 + quad * 4;
      if (EPI == 1) {
        if (out_bf16) {
#pragma unroll
          for (int r = 0; r < 4; ++r)
            ((__bf16*)Cout)[(size_t)(mbase + r) * N + n_idx] = (__bf16)acc[mt][nt][r];
        } else {
#pragma unroll
          for (int r = 0; r < 4; ++r)
            ((float*)Cout)[(size_t)(mbase + r) * N + n_idx] = acc[mt][nt][r];
        }
      } else {
        const int sel = n_idx >> 10;        // 0=Q 1=K 2=V (uniform per block)
        const int rem = n_idx & 1023;
        const int h   = rem >> 6;
        const int dh  = rem & 63;
        const int b   = mbase >> 11;        // same for r=0..3 (mbase % 4 == 0)
        const int l   = mbase & 2047;
        const int bh  = b * 16 + h;
        if (sel == 2) {
          bf16x4 pk;
#pragma unroll
          for (int r = 0; r < 4; ++r) pk[r] = (__bf16)acc[mt][nt][r];
          *(bf16x4*)&vtb[((size_t)bh * 64 + dh) * 2048 + l] = pk;   // 4 consecutive l
        } else {
          __bf16* dstb = (sel == 0 ? qb : kb) + ((size_t)bh * 2048 + l) * 64 + dh;
#pragma unroll
          for (int r = 0; r < 4; ++r)
            dstb[(size_t)r * 64] = (__bf16)acc[mt][nt][r];
        }
      }
    }
  }
}

// ---------------------------------------------------------------------------
// Flash attention: grid (L/128, B*H), 4 waves/block, 32 Q rows per wave.
// Fixed-shift softmax p = exp(s/8 - 8); l via ones-column (register B-frag).
// S^T = K Q^T with 16x16x32 MFMA; P goes through a small LDS round-trip to
// re-shape into the x32 PV A-fragment. The P scratch lives in the NEXT K/V
// staging buffer (dead during compute): wave w's P quarter == wave w's
// staging region, so P-write -> P-read -> stage-write are wave-private and
// one __syncthreads per K-tile suffices. K/V double-buffered via register
// prefetch issued before compute, written after (global latency hidden).
// ---------------------------------------------------------------------------
__launch_bounds__(256, 4)
__global__ void attn_kernel(const __bf16* __restrict__ qb,
                            const __bf16* __restrict__ kb,
                            const __bf16* __restrict__ vtb,
                            __bf16* __restrict__ ob /* [B,L,D] bf16 */)
{
  // [buf][ K(64 rows x 72) | V^T(64 rows x 72) ] ; quarter w (2304 elems) is
  // wave w's staging region AND its P scratch in the non-current buffer.
  __shared__ __align__(16) __bf16 S[2][2 * 64 * 72];

  const int tid  = threadIdx.x;
  const int wave = tid >> 6;
  const int lane = tid & 63;
  const int quad = lane >> 4;
  const int l16  = lane & 15;

  const int bh = blockIdx.y;
  const int b  = bh >> 4;
  const int h  = bh & 15;
  const int q0 = blockIdx.x * 128;

  const __bf16* Qp = qb  + (size_t)bh * 2048 * 64;
  const __bf16* Kp = kb  + (size_t)bh * 2048 * 64;
  const __bf16* Vp = vtb + (size_t)bh * 64 * 2048;

  const float C1 = 0.125f * 1.44269504f;
  const float C2 = -8.0f  * 1.44269504f;

  bf16x8 aq[2][2];
#pragma unroll
  for (int rt = 0; rt < 2; ++rt) {
    const __bf16* qrow = Qp + (size_t)(q0 + wave * 32 + rt * 16 + l16) * 64;
    aq[rt][0] = *(const bf16x8*)(qrow + quad * 8);
    aq[rt][1] = *(const bf16x8*)(qrow + 32 + quad * 8);
  }

  // ones column, x32 B-frag: B[k=quad*8+e][n=l16] = 1 at n==0
  bf16x8 onesb;
  {
    const __bf16 ov = (l16 == 0) ? (__bf16)1.0f : (__bf16)0.0f;
#pragma unroll
    for (int i = 0; i < 8; ++i) onesb[i] = ov;
  }

  floatx4 o[2][4], o5[2];
#pragma unroll
  for (int rt = 0; rt < 2; ++rt) {
    o5[rt] = (floatx4){0.f, 0.f, 0.f, 0.f};
#pragma unroll
    for (int dt = 0; dt < 4; ++dt) o[rt][dt] = (floatx4){0.f, 0.f, 0.f, 0.f};
  }

  // staging geometry: wave>>1 selects K(0)/V(1); wave&1 selects 32-row half.
  // per lane: 4 b128 chunks, row = srb + (lane>>3) + 8*i, col = (lane&7)*8.
  const int sarr = wave >> 1;
  const int srb  = (wave & 1) * 32;
  const int sr0  = lane >> 3;
  const int scol = (lane & 7) * 8;

  // prologue: stage tile 0 into S[0] (each wave its own quarter)
  {
    __bf16* dst = &S[0][sarr * (64 * 72)];
    if (sarr == 0) {
#pragma unroll
      for (int i = 0; i < 4; ++i) {
        const int row = srb + sr0 + 8 * i;
        *(bf16x8*)&dst[row * 72 + scol] = *(const bf16x8*)(Kp + (size_t)row * 64 + scol);
      }
    } else {
#pragma unroll
      for (int i = 0; i < 4; ++i) {
        const int row = srb + sr0 + 8 * i;
        *(bf16x8*)&dst[row * 72 + scol] = *(const bf16x8*)(Vp + (size_t)row * 2048 + scol);
      }
    }
  }
  __syncthreads();

  for (int kt = 0; kt < 32; ++kt) {
    const int cur = kt & 1;
    const int nxt = cur ^ 1;
    const int kn  = (((kt + 1) & 31) << 6);

    // issue next tile's global loads now; LDS-written after compute
    bf16x8 sreg[4];
    if (sarr == 0) {
#pragma unroll
      for (int i = 0; i < 4; ++i) {
        const int row = srb + sr0 + 8 * i;
        sreg[i] = *(const bf16x8*)(Kp + (size_t)(kn + row) * 64 + scol);
      }
    } else {
#pragma unroll
      for (int i = 0; i < 4; ++i) {
        const int row = srb + sr0 + 8 * i;
        sreg[i] = *(const bf16x8*)(Vp + (size_t)row * 2048 + kn + scol);
      }
    }

    const __bf16* Kc = &S[cur][0];
    const __bf16* Vc = &S[cur][64 * 72];
    __bf16*       Pq = &S[nxt][0] + wave * 2304;   // own quarter, 32 rows x 72

    // S^T = K Q^T (row=key, col=q): A=K-frags, B=Q-frags
    floatx4 st[2][4];
    __builtin_amdgcn_s_setprio(1);
#pragma unroll
    for (int nt = 0; nt < 4; ++nt) {
      const int krow = nt * 16 + l16;
      bf16x8 ak0 = *(const bf16x8*)&Kc[krow * 72 + quad * 8];
      bf16x8 ak1 = *(const bf16x8*)&Kc[krow * 72 + 32 + quad * 8];
#pragma unroll
      for (int rt = 0; rt < 2; ++rt) {
        floatx4 z = (floatx4){0.f, 0.f, 0.f, 0.f};
        z = __builtin_amdgcn_mfma_f32_16x16x32_bf16(ak0, aq[rt][0], z, 0, 0, 0);
        z = __builtin_amdgcn_mfma_f32_16x16x32_bf16(ak1, aq[rt][1], z, 0, 0, 0);
        st[rt][nt] = z;
      }
    }
    __builtin_amdgcn_s_setprio(0);

    // softmax + packed P write: lane holds keys nt*16+quad*4+{0..3} of q-row l16
#pragma unroll
    for (int rt = 0; rt < 2; ++rt) {
#pragma unroll
      for (int nt = 0; nt < 4; ++nt) {
        bf16x4 pk;
#pragma unroll
        for (int r = 0; r < 4; ++r)
          pk[r] = (__bf16)__builtin_amdgcn_exp2f(fmaf(st[rt][nt][r], C1, C2));
        *(bf16x4*)&Pq[(rt * 16 + l16) * 72 + nt * 16 + quad * 4] = pk;
      }
    }

    __builtin_amdgcn_wave_barrier();   // pin LDS write->read order (same wave)

    bf16x8 ap[2][2];
#pragma unroll
    for (int rt = 0; rt < 2; ++rt) {
      ap[rt][0] = *(const bf16x8*)&Pq[(rt * 16 + l16) * 72 + quad * 8];
      ap[rt][1] = *(const bf16x8*)&Pq[(rt * 16 + l16) * 72 + 32 + quad * 8];
    }

    __builtin_amdgcn_s_setprio(1);
#pragma unroll
    for (int dt = 0; dt < 4; ++dt) {
      const int vrow = dt * 16 + l16;
      bf16x8 bv0 = *(const bf16x8*)&Vc[vrow * 72 + quad * 8];
      bf16x8 bv1 = *(const bf16x8*)&Vc[vrow * 72 + 32 + quad * 8];
#pragma unroll
      for (int rt = 0; rt < 2; ++rt) {
        o[rt][dt] = __builtin_amdgcn_mfma_f32_16x16x32_bf16(ap[rt][0], bv0, o[rt][dt], 0, 0, 0);
        o[rt][dt] = __builtin_amdgcn_mfma_f32_16x16x32_bf16(ap[rt][1], bv1, o[rt][dt], 0, 0, 0);
      }
    }
    // ones-column: l accumulates in col 0 of o5
#pragma unroll
    for (int rt = 0; rt < 2; ++rt) {
      o5[rt] = __builtin_amdgcn_mfma_f32_16x16x32_bf16(ap[rt][0], onesb, o5[rt], 0, 0, 0);
      o5[rt] = __builtin_amdgcn_mfma_f32_16x16x32_bf16(ap[rt][1], onesb, o5[rt], 0, 0, 0);
    }
    __builtin_amdgcn_s_setprio(0);

    __builtin_amdgcn_wave_barrier();   // pin: stage writes stay below P reads (WAR, same quarter)

    // stage tile kt+1 into own quarter of S[nxt] (overwrites consumed P)
    {
      __bf16* dst = &S[nxt][sarr * (64 * 72)];
#pragma unroll
      for (int i = 0; i < 4; ++i) {
        const int row = srb + sr0 + 8 * i;
        *(bf16x8*)&dst[row * 72 + scol] = sreg[i];
      }
    }
    __syncthreads();   // next tile (and all P consumption) complete
  }

#pragma unroll
  for (int rt = 0; rt < 2; ++rt)
#pragma unroll
    for (int r = 0; r < 4; ++r) {
      const float lv  = row16_sum(l16 == 0 ? o5[rt][r] : 0.f);
      const float inv = 1.f / lv;
      const size_t rowbase =
          ((size_t)b * 2048 + q0 + wave * 32 + rt * 16 + quad * 4 + r) * 1024 + h * 64;
#pragma unroll
      for (int dt = 0; dt < 4; ++dt)
        ob[rowbase + dt * 16 + l16] = (__bf16)(o[rt][dt][r] * inv);
    }
}

// ---------------------------------------------------------------------------
extern "C" void kernel_launch(void* const* d_in, const int* in_sizes, int n_in,
                              void* d_out, int out_size, void* d_ws, size_t ws_size,
                              hipStream_t stream)
{
  (void)in_sizes; (void)n_in; (void)out_size; (void)ws_size;

  const void* x     = d_in[0];
  const void* wqkv  = d_in[1];
  const void* wproj = d_in[2];

  const size_t NX    = (size_t)8192 * 1024;
  const size_t NWQKV = (size_t)3072 * 1024;
  const size_t NWPRJ = (size_t)1024 * 1024;

  __bf16* qbuf   = (__bf16*)d_ws;
  __bf16* kbuf   = qbuf + NX;
  __bf16* vtbuf  = kbuf + NX;
  __bf16* abuf   = vtbuf + NX;
  __bf16* xb     = abuf + NX;
  __bf16* wqkvb  = xb + NX;
  __bf16* wprojb = wqkvb + NWQKV;

  dim3 blk(256);

  cvt3_kernel<<<dim3((NX + NWQKV + NWPRJ) / 2048), blk, 0, stream>>>(
      x, xb, NX / 8, wqkv, wqkvb, NWQKV / 8, wproj, wprojb);

  gemm_bt_kernel<0><<<dim3(24 * 64), blk, 0, stream>>>(
      xb, wqkvb, nullptr, nullptr, qbuf, kbuf, vtbuf, 8192, 3072, 1024);

  attn_kernel<<<dim3(2048 / 128, 64), blk, 0, stream>>>(qbuf, kbuf, vtbuf, abuf);

  gemm_bt_kernel<1><<<dim3(8 * 64), blk, 0, stream>>>(
      abuf, wprojb, wproj, d_out, nullptr, nullptr, nullptr, 8192, 1024, 1024);
}

// Round 7
// 287.552 us; speedup vs baseline: 1.7106x; 1.0019x over previous
//
#include <hip/hip_runtime.h>
#include <hip/hip_bf16.h>

// B=4, L=2048, D=1024, H=16, DH=64.  out = proj( softmax(QK^T/8) V ), fused QKV.
// Inputs fp32 (runtime-detected), compute bf16 MFMA, output dtype follows input.
// R15: gemm<0> replaced by gemm_qkv_kernel — 256x256 tile, BK=32, 4-deep LDS
//      ring (128 KB), ONE s_barrier + counted s_waitcnt vmcnt(4) per K-tile
//      (loads for tile t+2 issued during tile t; never drains in-loop — the
//      m97 ~900TF ceiling was the per-tile vmcnt(0) drain in __syncthreads).
//      Both-sides XOR swizzle (chunk ^= (row>>1)&3): pre-swizzled global src
//      for global_load_lds + swizzled ds_read => 2-way conflicts (free).
//      8 waves 2Mx4N, per-wave C 128x64, setprio around MFMA cluster,
//      XCD-chunked block decode (8 xcds x 48 tiles, n-outer/m-inner).
//      Bit-identical accumulation order => absmax must stay 0.001953125.
//      attn = R10-exact (93-95us proven). gemm<1> = m97 kernel at (256,2).

typedef __bf16  bf16x8  __attribute__((ext_vector_type(8)));
typedef __bf16  bf16x4  __attribute__((ext_vector_type(4)));
typedef float   floatx4 __attribute__((ext_vector_type(4)));

__device__ __forceinline__ void async_ld16(const void* g, void* lds_base_uniform) {
  __builtin_amdgcn_global_load_lds(
      (const __attribute__((address_space(1))) void*)g,
      (__attribute__((address_space(3))) void*)lds_base_uniform,
      16, 0, 0);
}

// bf16-vs-fp32 probe: even uint16s of bf16 N(0,s) data have sane exponents;
// fp32 low-mantissa halves are uniform.
__device__ __forceinline__ int detect_bf16(const void* p) {
  const unsigned short* u = (const unsigned short*)p;
  int sane = 0;
#pragma unroll 4
  for (int i = 0; i < 64; ++i) {
    unsigned short w = u[2 * i];
    int e = (w >> 7) & 0xFF;
    sane += (w == 0 || (e >= 100 && e <= 150)) ? 1 : 0;
  }
  return sane >= 32;
}

__device__ __forceinline__ bf16x8 ld8_f32cvt(const void* base, size_t elem) {
  const float* p = (const float*)base + elem;
  floatx4 u0 = *(const floatx4*)p;
  floatx4 u1 = *(const floatx4*)(p + 4);
  bf16x8 v;
  v[0] = (__bf16)u0[0]; v[1] = (__bf16)u0[1]; v[2] = (__bf16)u0[2]; v[3] = (__bf16)u0[3];
  v[4] = (__bf16)u1[0]; v[5] = (__bf16)u1[1]; v[6] = (__bf16)u1[2]; v[7] = (__bf16)u1[3];
  return v;
}

// DPP cross-lane sum within 16-lane rows (verified R4-R7).
template<int CTRL>
__device__ __forceinline__ float dpp_f(float x) {
  return __builtin_bit_cast(float,
      __builtin_amdgcn_update_dpp(0, __builtin_bit_cast(int, x), CTRL, 0xF, 0xF, true));
}
__device__ __forceinline__ float row16_sum(float x) {
  x += dpp_f<0xB1>(x);
  x += dpp_f<0x4E>(x);
  x += dpp_f<0x141>(x);
  x += dpp_f<0x140>(x);
  return x;
}

// ---------------------------------------------------------------------------
// fused dtype-normalizing copy over 3 segments (segment starts block-aligned)
// ---------------------------------------------------------------------------
__launch_bounds__(256)
__global__ void cvt3_kernel(const void* __restrict__ s0, __bf16* __restrict__ d0, int n0,
                            const void* __restrict__ s1, __bf16* __restrict__ d1, int n1,
                            const void* __restrict__ s2, __bf16* __restrict__ d2) {
  int u = blockIdx.x * blockDim.x + threadIdx.x;
  const void* src; __bf16* dst;
  if (u < n0)           { src = s0; dst = d0; }
  else if (u < n0 + n1) { src = s1; dst = d1; u -= n0; }
  else                  { src = s2; dst = d2; u -= n0 + n1; }
  const int is_bf16 = detect_bf16(src);
  const size_t e = (size_t)u * 8;
  if (is_bf16) *(bf16x8*)(dst + e) = *(const bf16x8*)((const __bf16*)src + e);
  else         *(bf16x8*)(dst + e) = ld8_f32cvt(src, e);
}

// ---------------------------------------------------------------------------
// gemm_qkv: C[8192,3072] = X[8192,1024] * Wqkv[3072,1024]^T, scattered to
// Q/K [BH,L,DH] and VT [BH,DH,L].  256x256 tile, BK=32, 4-deep LDS ring.
// Counted pipeline: tile t+2's 4 global_load_lds issued during tile t; at
// tile t head: s_waitcnt vmcnt(4) (t+1's 4 outstanding => t's retired, in-
// order) + ONE s_barrier. Buffer (t+2)&3 was last read at t-2, 2 barriers
// before the issue point => no WAR race. LDS chunk swizzle on BOTH sides:
// read chunk_phys = quad ^ ((l16>>1)&3); staging global col chunk =
// (t&3)^((t>>3)&3) (inverse). ds_read banks: 8 groups x 2 lanes = free.
// ---------------------------------------------------------------------------
__launch_bounds__(512, 2)
__global__ void gemm_qkv_kernel(const __bf16* __restrict__ A,
                                const __bf16* __restrict__ B,
                                __bf16* __restrict__ qb,
                                __bf16* __restrict__ kb,
                                __bf16* __restrict__ vtb)
{
  __shared__ __align__(16) __bf16 SM[4 * 16384];  // ring buf b: A @ b*16384, B @ +8192 (elems)

  const int flat = blockIdx.x;          // 384 blocks = 8 xcds * 48
  const int xcd  = flat & 7;
  const int j    = flat >> 3;           // n-outer (12), m_loc-inner (4)
  const int m0   = ((xcd << 2) | (j & 3)) << 8;
  const int n0   = (j >> 2) << 8;

  const int tid  = threadIdx.x;
  const int wave = tid >> 6;            // 0..7
  const int lane = tid & 63;
  const int quad = lane >> 4;
  const int l16  = lane & 15;
  const int wm   = wave >> 2;           // 0..1
  const int wn   = wave & 3;            // 0..3

  // staging: thread t -> LDS row i*128+(t>>2), phys chunk t&3; logical col
  // chunk = (t&3)^((t>>3)&3)  [== phys ^ ((row>>1)&3), the read swizzle]
  const int srow = tid >> 2;            // 0..127 (+ i*128)
  const int scc  = (((tid & 3) ^ ((tid >> 3) & 3)) << 3);   // col elems

  auto STAGE = [&](int buf, int k0) {
    char* base = (char*)SM + buf * 32768;
#pragma unroll
    for (int i = 0; i < 2; ++i) {
      async_ld16(A + (size_t)(m0 + i * 128 + srow) * 1024 + k0 + scc,
                 base + i * 8192 + wave * 1024);
      async_ld16(B + (size_t)(n0 + i * 128 + srow) * 1024 + k0 + scc,
                 base + 16384 + i * 8192 + wave * 1024);
    }
  };

  floatx4 acc[8][4];
#pragma unroll
  for (int i = 0; i < 8; ++i)
#pragma unroll
    for (int n = 0; n < 4; ++n) acc[i][n] = (floatx4){0.f, 0.f, 0.f, 0.f};

  STAGE(0, 0);
  STAGE(1, 32);

  const int cswz = quad ^ ((l16 >> 1) & 3);   // phys chunk for frag reads

  for (int t = 0; t < 32; ++t) {
    // wave's own loads for tile t retired (t+1's 4 may remain in flight);
    // barrier => every wave's are; fence pins LDS reads below.
    if (t < 31) asm volatile("s_waitcnt vmcnt(4)" ::: "memory");
    else        asm volatile("s_waitcnt vmcnt(0)" ::: "memory");
    __builtin_amdgcn_s_barrier();
    asm volatile("" ::: "memory");

    if (t + 2 < 32) STAGE((t + 2) & 3, (t + 2) << 5);

    const __bf16* As_ = SM + (t & 3) * 16384;
    const __bf16* Bs_ = As_ + 8192;

    bf16x8 bfr[4];
#pragma unroll
    for (int nf = 0; nf < 4; ++nf)
      bfr[nf] = *(const bf16x8*)&Bs_[(wn * 64 + nf * 16 + l16) * 32 + cswz * 8];

    __builtin_amdgcn_s_setprio(1);
#pragma unroll
    for (int mf = 0; mf < 8; ++mf) {
      bf16x8 af = *(const bf16x8*)&As_[(wm * 128 + mf * 16 + l16) * 32 + cswz * 8];
#pragma unroll
      for (int nf = 0; nf < 4; ++nf)
        acc[mf][nf] = __builtin_amdgcn_mfma_f32_16x16x32_bf16(af, bfr[nf], acc[mf][nf], 0, 0, 0);
    }
    __builtin_amdgcn_s_setprio(0);
  }

  // scatter epilogue (same math as R2 EPI=0, re-indexed for 2x4 wave grid)
  // C/D layout: col = lane&15, row = quad*4 + reg
#pragma unroll
  for (int mf = 0; mf < 8; ++mf) {
#pragma unroll
    for (int nf = 0; nf < 4; ++nf) {
      const int n_idx = n0 + wn * 64 + nf * 16 + l16;
      const int mbase = m0 + wm * 128 + mf * 16 + quad * 4;
      const int sel = n_idx >> 10;        // 0=Q 1=K 2=V (uniform per block)
      const int rem = n_idx & 1023;
      const int h   = rem >> 6;
      const int dh  = rem & 63;
      const int b   = mbase >> 11;        // same for r=0..3 (mbase % 4 == 0)
      const int l   = mbase & 2047;
      const int bh  = b * 16 + h;
      if (sel == 2) {
        bf16x4 pk;
#pragma unroll
        for (int r = 0; r < 4; ++r) pk[r] = (__bf16)acc[mf][nf][r];
        *(bf16x4*)&vtb[((size_t)bh * 64 + dh) * 2048 + l] = pk;   // 4 consecutive l
      } else {
        __bf16* dstb = (sel == 0 ? qb : kb) + ((size_t)bh * 2048 + l) * 64 + dh;
#pragma unroll
        for (int r = 0; r < 4; ++r)
          dstb[(size_t)r * 64] = (__bf16)acc[mf][nf][r];
      }
    }
  }
}

// ---------------------------------------------------------------------------
// gemm_bt: C[M,N] = A[M,K] * B[N,K]^T  (m97: 128x128 tile, BK=32, async
// staging). Used for the output projection only (EPI=1): row-major store,
// dtype per runtime probe of `oprobe`. XCD-local m-slab decode.
// ---------------------------------------------------------------------------
template<int EPI>
__launch_bounds__(256, 2)
__global__ void gemm_bt_kernel(const __bf16* __restrict__ A,
                               const __bf16* __restrict__ B,
                               const void* __restrict__ oprobe,
                               void* __restrict__ Cout,
                               int M, int N, int K)
{
  __shared__ __align__(16) __bf16 As[128 * 32];
  __shared__ __align__(16) __bf16 Bs[128 * 32];

  const int flat = blockIdx.x;
  const int m0 = (((flat & 7) << 3) | ((flat >> 3) & 7)) << 7;
  const int n0 = (flat >> 6) << 7;

  const int tid  = threadIdx.x;
  const int wave = tid >> 6;
  const int lane = tid & 63;
  const int quad = lane >> 4;
  const int l16  = lane & 15;
  const int wm   = wave >> 1;
  const int wn   = wave & 1;

  const int r_in   = lane >> 2;
  const int cchunk = lane & 3;

  const __bf16* Ab = A + (size_t)m0 * K;
  const __bf16* Bb = B + (size_t)n0 * K;

  floatx4 acc[4][4];
#pragma unroll
  for (int i = 0; i < 4; ++i)
#pragma unroll
    for (int j = 0; j < 4; ++j)
      acc[i][j] = (floatx4){0.f, 0.f, 0.f, 0.f};

  const int ca0 = wave * 2;
  for (int k0 = 0; k0 < K; k0 += 32) {
#pragma unroll
    for (int i = 0; i < 2; ++i) {
      const int ca  = ca0 + i;
      const int row = ca * 16 + r_in;
      async_ld16(Ab + (size_t)row * K + k0 + cchunk * 8, (char*)As + ca * 1024);
      async_ld16(Bb + (size_t)row * K + k0 + cchunk * 8, (char*)Bs + ca * 1024);
    }
    __syncthreads();

    bf16x8 af[4], bfr[4];
#pragma unroll
    for (int tt = 0; tt < 4; ++tt) {
      af[tt]  = *(const bf16x8*)&As[(wm * 64 + tt * 16 + l16) * 32 + quad * 8];
      bfr[tt] = *(const bf16x8*)&Bs[(wn * 64 + tt * 16 + l16) * 32 + quad * 8];
    }
#pragma unroll
    for (int mt = 0; mt < 4; ++mt)
#pragma unroll
      for (int nt = 0; nt < 4; ++nt)
        acc[mt][nt] = __builtin_amdgcn_mfma_f32_16x16x32_bf16(af[mt], bfr[nt], acc[mt][nt], 0, 0, 0);
    __syncthreads();
  }

  const int out_bf16 = detect_bf16(oprobe);

  // C/D layout: col = lane&15, row = quad*4 + reg
#pragma unroll
  for (int mt = 0; mt < 4; ++mt) {
#pragma unroll
    for (int nt = 0; nt < 4; ++nt) {
      const int n_idx = n0 + wn * 64 + nt * 16 + l16;
      const int mbase = m0 + wm * 64 + mt * 16 + quad * 4;
      if (out_bf16) {
#pragma unroll
        for (int r = 0; r < 4; ++r)
          ((__bf16*)Cout)[(size_t)(mbase + r) * N + n_idx] = (__bf16)acc[mt][nt][r];
      } else {
#pragma unroll
        for (int r = 0; r < 4; ++r)
          ((float*)Cout)[(size_t)(mbase + r) * N + n_idx] = acc[mt][nt][r];
      }
    }
  }
}

// ---------------------------------------------------------------------------
// Flash attention: grid (L/128, B*H), 4 waves/block, 32 Q rows per wave.
// Fixed-shift softmax p = exp(s/8 - 8); l via ones-column (register B-frag).
// S^T = K Q^T with 16x16x32 MFMA; P goes through a small LDS round-trip to
// re-shape into the x32 PV A-fragment. The P scratch lives in the NEXT K/V
// staging buffer (dead during compute): wave w's P quarter == wave w's
// staging region, so P-write -> P-read -> stage-write are wave-private and
// one __syncthreads per K-tile suffices. K/V double-buffered via register
// prefetch issued before compute, written after (global latency hidden).
// ---------------------------------------------------------------------------
__launch_bounds__(256, 4)
__global__ void attn_kernel(const __bf16* __restrict__ qb,
                            const __bf16* __restrict__ kb,
                            const __bf16* __restrict__ vtb,
                            __bf16* __restrict__ ob /* [B,L,D] bf16 */)
{
  // [buf][ K(64 rows x 72) | V^T(64 rows x 72) ] ; quarter w (2304 elems) is
  // wave w's staging region AND its P scratch in the non-current buffer.
  __shared__ __align__(16) __bf16 S[2][2 * 64 * 72];

  const int tid  = threadIdx.x;
  const int wave = tid >> 6;
  const int lane = tid & 63;
  const int quad = lane >> 4;
  const int l16  = lane & 15;

  const int bh = blockIdx.y;
  const int b  = bh >> 4;
  const int h  = bh & 15;
  const int q0 = blockIdx.x * 128;

  const __bf16* Qp = qb  + (size_t)bh * 2048 * 64;
  const __bf16* Kp = kb  + (size_t)bh * 2048 * 64;
  const __bf16* Vp = vtb + (size_t)bh * 64 * 2048;

  const float C1 = 0.125f * 1.44269504f;
  const float C2 = -8.0f  * 1.44269504f;

  bf16x8 aq[2][2];
#pragma unroll
  for (int rt = 0; rt < 2; ++rt) {
    const __bf16* qrow = Qp + (size_t)(q0 + wave * 32 + rt * 16 + l16) * 64;
    aq[rt][0] = *(const bf16x8*)(qrow + quad * 8);
    aq[rt][1] = *(const bf16x8*)(qrow + 32 + quad * 8);
  }

  // ones column, x32 B-frag: B[k=quad*8+e][n=l16] = 1 at n==0
  bf16x8 onesb;
  {
    const __bf16 ov = (l16 == 0) ? (__bf16)1.0f : (__bf16)0.0f;
#pragma unroll
    for (int i = 0; i < 8; ++i) onesb[i] = ov;
  }

  floatx4 o[2][4], o5[2];
#pragma unroll
  for (int rt = 0; rt < 2; ++rt) {
    o5[rt] = (floatx4){0.f, 0.f, 0.f, 0.f};
#pragma unroll
    for (int dt = 0; dt < 4; ++dt) o[rt][dt] = (floatx4){0.f, 0.f, 0.f, 0.f};
  }

  // staging geometry: wave>>1 selects K(0)/V(1); wave&1 selects 32-row half.
  // per lane: 4 b128 chunks, row = srb + (lane>>3) + 8*i, col = (lane&7)*8.
  const int sarr = wave >> 1;
  const int srb  = (wave & 1) * 32;
  const int sr0  = lane >> 3;
  const int scol = (lane & 7) * 8;

  // prologue: stage tile 0 into S[0] (each wave its own quarter)
  {
    __bf16* dst = &S[0][sarr * (64 * 72)];
    if (sarr == 0) {
#pragma unroll
      for (int i = 0; i < 4; ++i) {
        const int row = srb + sr0 + 8 * i;
        *(bf16x8*)&dst[row * 72 + scol] = *(const bf16x8*)(Kp + (size_t)row * 64 + scol);
      }
    } else {
#pragma unroll
      for (int i = 0; i < 4; ++i) {
        const int row = srb + sr0 + 8 * i;
        *(bf16x8*)&dst[row * 72 + scol] = *(const bf16x8*)(Vp + (size_t)row * 2048 + scol);
      }
    }
  }
  __syncthreads();

  for (int kt = 0; kt < 32; ++kt) {
    const int cur = kt & 1;
    const int nxt = cur ^ 1;
    const int kn  = (((kt + 1) & 31) << 6);

    // issue next tile's global loads now; LDS-written after compute
    bf16x8 sreg[4];
    if (sarr == 0) {
#pragma unroll
      for (int i = 0; i < 4; ++i) {
        const int row = srb + sr0 + 8 * i;
        sreg[i] = *(const bf16x8*)(Kp + (size_t)(kn + row) * 64 + scol);
      }
    } else {
#pragma unroll
      for (int i = 0; i < 4; ++i) {
        const int row = srb + sr0 + 8 * i;
        sreg[i] = *(const bf16x8*)(Vp + (size_t)row * 2048 + kn + scol);
      }
    }

    const __bf16* Kc = &S[cur][0];
    const __bf16* Vc = &S[cur][64 * 72];
    __bf16*       Pq = &S[nxt][0] + wave * 2304;   // own quarter, 32 rows x 72

    // S^T = K Q^T (row=key, col=q): A=K-frags, B=Q-frags
    floatx4 st[2][4];
    __builtin_amdgcn_s_setprio(1);
#pragma unroll
    for (int nt = 0; nt < 4; ++nt) {
      const int krow = nt * 16 + l16;
      bf16x8 ak0 = *(const bf16x8*)&Kc[krow * 72 + quad * 8];
      bf16x8 ak1 = *(const bf16x8*)&Kc[krow * 72 + 32 + quad * 8];
#pragma unroll
      for (int rt = 0; rt < 2; ++rt) {
        floatx4 z = (floatx4){0.f, 0.f, 0.f, 0.f};
        z = __builtin_amdgcn_mfma_f32_16x16x32_bf16(ak0, aq[rt][0], z, 0, 0, 0);
        z = __builtin_amdgcn_mfma_f32_16x16x32_bf16(ak1, aq[rt][1], z, 0, 0, 0);
        st[rt][nt] = z;
      }
    }
    __builtin_amdgcn_s_setprio(0);

    // softmax + packed P write: lane holds keys nt*16+quad*4+{0..3} of q-row l16
#pragma unroll
    for (int rt = 0; rt < 2; ++rt) {
#pragma unroll
      for (int nt = 0; nt < 4; ++nt) {
        bf16x4 pk;
#pragma unroll
        for (int r = 0; r < 4; ++r)
          pk[r] = (__bf16)__builtin_amdgcn_exp2f(fmaf(st[rt][nt][r], C1, C2));
        *(bf16x4*)&Pq[(rt * 16 + l16) * 72 + nt * 16 + quad * 4] = pk;
      }
    }

    __builtin_amdgcn_wave_barrier();   // pin LDS write->read order (same wave)

    bf16x8 ap[2][2];
#pragma unroll
    for (int rt = 0; rt < 2; ++rt) {
      ap[rt][0] = *(const bf16x8*)&Pq[(rt * 16 + l16) * 72 + quad * 8];
      ap[rt][1] = *(const bf16x8*)&Pq[(rt * 16 + l16) * 72 + 32 + quad * 8];
    }

    __builtin_amdgcn_s_setprio(1);
#pragma unroll
    for (int dt = 0; dt < 4; ++dt) {
      const int vrow = dt * 16 + l16;
      bf16x8 bv0 = *(const bf16x8*)&Vc[vrow * 72 + quad * 8];
      bf16x8 bv1 = *(const bf16x8*)&Vc[vrow * 72 + 32 + quad * 8];
#pragma unroll
      for (int rt = 0; rt < 2; ++rt) {
        o[rt][dt] = __builtin_amdgcn_mfma_f32_16x16x32_bf16(ap[rt][0], bv0, o[rt][dt], 0, 0, 0);
        o[rt][dt] = __builtin_amdgcn_mfma_f32_16x16x32_bf16(ap[rt][1], bv1, o[rt][dt], 0, 0, 0);
      }
    }
    // ones-column: l accumulates in col 0 of o5
#pragma unroll
    for (int rt = 0; rt < 2; ++rt) {
      o5[rt] = __builtin_amdgcn_mfma_f32_16x16x32_bf16(ap[rt][0], onesb, o5[rt], 0, 0, 0);
      o5[rt] = __builtin_amdgcn_mfma_f32_16x16x32_bf16(ap[rt][1], onesb, o5[rt], 0, 0, 0);
    }
    __builtin_amdgcn_s_setprio(0);

    __builtin_amdgcn_wave_barrier();   // pin: stage writes stay below P reads (WAR, same quarter)

    // stage tile kt+1 into own quarter of S[nxt] (overwrites consumed P)
    {
      __bf16* dst = &S[nxt][sarr * (64 * 72)];
#pragma unroll
      for (int i = 0; i < 4; ++i) {
        const int row = srb + sr0 + 8 * i;
        *(bf16x8*)&dst[row * 72 + scol] = sreg[i];
      }
    }
    __syncthreads();   // next tile (and all P consumption) complete
  }

#pragma unroll
  for (int rt = 0; rt < 2; ++rt)
#pragma unroll
    for (int r = 0; r < 4; ++r) {
      const float lv  = row16_sum(l16 == 0 ? o5[rt][r] : 0.f);
      const float inv = 1.f / lv;
      const size_t rowbase =
          ((size_t)b * 2048 + q0 + wave * 32 + rt * 16 + quad * 4 + r) * 1024 + h * 64;
#pragma unroll
      for (int dt = 0; dt < 4; ++dt)
        ob[rowbase + dt * 16 + l16] = (__bf16)(o[rt][dt][r] * inv);
    }
}

// ---------------------------------------------------------------------------
extern "C" void kernel_launch(void* const* d_in, const int* in_sizes, int n_in,
                              void* d_out, int out_size, void* d_ws, size_t ws_size,
                              hipStream_t stream)
{
  (void)in_sizes; (void)n_in; (void)out_size; (void)ws_size;

  const void* x     = d_in[0];
  const void* wqkv  = d_in[1];
  const void* wproj = d_in[2];

  const size_t NX    = (size_t)8192 * 1024;
  const size_t NWQKV = (size_t)3072 * 1024;
  const size_t NWPRJ = (size_t)1024 * 1024;

  __bf16* qbuf   = (__bf16*)d_ws;
  __bf16* kbuf   = qbuf + NX;
  __bf16* vtbuf  = kbuf + NX;
  __bf16* abuf   = vtbuf + NX;
  __bf16* xb     = abuf + NX;
  __bf16* wqkvb  = xb + NX;
  __bf16* wprojb = wqkvb + NWQKV;

  cvt3_kernel<<<dim3((NX + NWQKV + NWPRJ) / 2048), dim3(256), 0, stream>>>(
      x, xb, NX / 8, wqkv, wqkvb, NWQKV / 8, wproj, wprojb);

  gemm_qkv_kernel<<<dim3(384), dim3(512), 0, stream>>>(
      xb, wqkvb, qbuf, kbuf, vtbuf);

  attn_kernel<<<dim3(2048 / 128, 64), dim3(256), 0, stream>>>(qbuf, kbuf, vtbuf, abuf);

  gemm_bt_kernel<1><<<dim3(8 * 64), dim3(256), 0, stream>>>(
      abuf, wprojb, wproj, d_out, 8192, 1024, 1024);
}

// Round 8
// 284.791 us; speedup vs baseline: 1.7272x; 1.0097x over previous
//
#include <hip/hip_runtime.h>
#include <hip/hip_bf16.h>

// B=4, L=2048, D=1024, H=16, DH=64.  out = proj( softmax(QK^T/8) V ), fused QKV.
// Inputs fp32 (runtime-detected), compute bf16 MFMA, output dtype follows input.
// R16: both GEMMs -> ONE persistent 128^2-tile kernel, grid 512 (2 blocks/CU,
//      zero tail). Per block: tiles {bx, bx+512, bx+1024} (same m-slab -> A
//      staged once/block; logical staging traffic 768->512MB). R15's verified
//      counted pipeline (4-deep LDS ring, vmcnt(4) at step head, ONE s_barrier,
//      never drains mid-kernel) runs CONTINUOUSLY across tile boundaries;
//      epilogue overlaps next tile's prefetch. R15's both-sides XOR swizzle
//      kept (row-swizzle bits independent of the i-half at 128^2 — verified).
//      Epilogues + accumulation order identical to R2 => bit-identical output.
//      attn = R10-exact (93us proven), cvt3 = R2-exact.

typedef __bf16  bf16x8  __attribute__((ext_vector_type(8)));
typedef __bf16  bf16x4  __attribute__((ext_vector_type(4)));
typedef float   floatx4 __attribute__((ext_vector_type(4)));

__device__ __forceinline__ void async_ld16(const void* g, void* lds_base_uniform) {
  __builtin_amdgcn_global_load_lds(
      (const __attribute__((address_space(1))) void*)g,
      (__attribute__((address_space(3))) void*)lds_base_uniform,
      16, 0, 0);
}

// bf16-vs-fp32 probe: even uint16s of bf16 N(0,s) data have sane exponents;
// fp32 low-mantissa halves are uniform.
__device__ __forceinline__ int detect_bf16(const void* p) {
  const unsigned short* u = (const unsigned short*)p;
  int sane = 0;
#pragma unroll 4
  for (int i = 0; i < 64; ++i) {
    unsigned short w = u[2 * i];
    int e = (w >> 7) & 0xFF;
    sane += (w == 0 || (e >= 100 && e <= 150)) ? 1 : 0;
  }
  return sane >= 32;
}

__device__ __forceinline__ bf16x8 ld8_f32cvt(const void* base, size_t elem) {
  const float* p = (const float*)base + elem;
  floatx4 u0 = *(const floatx4*)p;
  floatx4 u1 = *(const floatx4*)(p + 4);
  bf16x8 v;
  v[0] = (__bf16)u0[0]; v[1] = (__bf16)u0[1]; v[2] = (__bf16)u0[2]; v[3] = (__bf16)u0[3];
  v[4] = (__bf16)u1[0]; v[5] = (__bf16)u1[1]; v[6] = (__bf16)u1[2]; v[7] = (__bf16)u1[3];
  return v;
}

// DPP cross-lane sum within 16-lane rows (verified R4-R7).
template<int CTRL>
__device__ __forceinline__ float dpp_f(float x) {
  return __builtin_bit_cast(float,
      __builtin_amdgcn_update_dpp(0, __builtin_bit_cast(int, x), CTRL, 0xF, 0xF, true));
}
__device__ __forceinline__ float row16_sum(float x) {
  x += dpp_f<0xB1>(x);
  x += dpp_f<0x4E>(x);
  x += dpp_f<0x141>(x);
  x += dpp_f<0x140>(x);
  return x;
}

// ---------------------------------------------------------------------------
// fused dtype-normalizing copy over 3 segments (segment starts block-aligned)
// ---------------------------------------------------------------------------
__launch_bounds__(256)
__global__ void cvt3_kernel(const void* __restrict__ s0, __bf16* __restrict__ d0, int n0,
                            const void* __restrict__ s1, __bf16* __restrict__ d1, int n1,
                            const void* __restrict__ s2, __bf16* __restrict__ d2) {
  int u = blockIdx.x * blockDim.x + threadIdx.x;
  const void* src; __bf16* dst;
  if (u < n0)           { src = s0; dst = d0; }
  else if (u < n0 + n1) { src = s1; dst = d1; u -= n0; }
  else                  { src = s2; dst = d2; u -= n0 + n1; }
  const int is_bf16 = detect_bf16(src);
  const size_t e = (size_t)u * 8;
  if (is_bf16) *(bf16x8*)(dst + e) = *(const bf16x8*)((const __bf16*)src + e);
  else         *(bf16x8*)(dst + e) = ld8_f32cvt(src, e);
}

// ---------------------------------------------------------------------------
// gemm_ptile: persistent 128x128-tile GEMM, C = A[M,1024] * B[N,1024]^T.
// Grid 512 (2 blocks/CU). Block bx owns tiles {bx + i*512, i<ntiles/512}; m97
// decode (t&63 -> m-tile, t>>6 -> n-tile) makes them share one m-slab -> A is
// staged once per block. Counted pipeline across ALL steps s=0..32*tb-1:
//   head: s_waitcnt vmcnt(4) (step s+1's 4 loads stay in flight; epilogue
//   stores drain incidentally once per tile) + ONE s_barrier;
//   then STAGE(s+2) into ring buf (s+2)&3 (last read at s-2, 2 barriers ago).
// Both-sides XOR swizzle (R15-verified): stage logical col chunk
// (tid&3)^((tid>>3)&3); read phys chunk quad^((l16>>1)&3). The row's swizzle
// bits (row>>1)&3 equal (tid>>3)&3 / (l16>>1)&3 for both i-halves and all
// wm/tt -> identical to the verified 256^2 instance.
// EPI 0: scatter to Q/K [BH,L,DH] + VT [BH,DH,L].  EPI 1: row-major, dtype
// per runtime probe.  Accumulation order identical to R2 (bit-identical).
// ---------------------------------------------------------------------------
template<int EPI>
__launch_bounds__(256, 2)
__global__ void gemm_ptile_kernel(const __bf16* __restrict__ A,
                                  const __bf16* __restrict__ B,
                                  const void* __restrict__ oprobe,
                                  void* __restrict__ Cout,
                                  __bf16* __restrict__ qb,
                                  __bf16* __restrict__ kb,
                                  __bf16* __restrict__ vtb,
                                  int ntiles, int N)
{
  __shared__ __align__(16) __bf16 SM[4 * 8192];   // ring buf b: A @ b*8192, B @ +4096 (elems)

  const int bx   = blockIdx.x;          // 512
  const int tid  = threadIdx.x;
  const int wave = tid >> 6;
  const int lane = tid & 63;
  const int quad = lane >> 4;
  const int l16  = lane & 15;
  const int wm   = wave >> 1;
  const int wn   = wave & 1;

  const int tb = ntiles >> 9;           // tiles per block (3 for QKV, 1 for proj)
  const int S  = tb << 5;               // total k-steps

  // staging: thread t -> row i*64+(t>>2), phys chunk t&3, logical col chunk
  // (t&3)^((t>>3)&3)  [= phys ^ ((row>>1)&3) for both i-halves]
  const int srow = tid >> 2;            // 0..63
  const int scc  = (((tid & 3) ^ ((tid >> 3) & 3)) << 3);

  auto DECODE_M = [&](int t) { return (((t & 7) << 3) | ((t >> 3) & 7)) << 7; };
  auto DECODE_N = [&](int t) { return (t >> 6) << 7; };

  auto STAGE = [&](int s) {
    const int t  = bx + ((s >> 5) << 9);
    const int m0 = DECODE_M(t);
    const int n0 = DECODE_N(t);
    const int k0 = (s & 31) << 5;
    char* base = (char*)SM + (s & 3) * 16384;
#pragma unroll
    for (int i = 0; i < 2; ++i) {
      async_ld16(A + (size_t)(m0 + i * 64 + srow) * 1024 + k0 + scc,
                 base + i * 4096 + wave * 1024);
      async_ld16(B + (size_t)(n0 + i * 64 + srow) * 1024 + k0 + scc,
                 base + 8192 + i * 4096 + wave * 1024);
    }
  };

  const int out_bf16 = (EPI == 1) ? detect_bf16(oprobe) : 0;
  const int cswz = quad ^ ((l16 >> 1) & 3);   // phys chunk for frag reads

  floatx4 acc[4][4];
#pragma unroll
  for (int i = 0; i < 4; ++i)
#pragma unroll
    for (int j = 0; j < 4; ++j) acc[i][j] = (floatx4){0.f, 0.f, 0.f, 0.f};

  STAGE(0);
  STAGE(1);

  for (int s = 0; s < S; ++s) {
    if (s < S - 1) asm volatile("s_waitcnt vmcnt(4)" ::: "memory");
    else           asm volatile("s_waitcnt vmcnt(0)" ::: "memory");
    __builtin_amdgcn_s_barrier();
    asm volatile("" ::: "memory");

    if (s + 2 < S) STAGE(s + 2);

    const __bf16* As_ = SM + (s & 3) * 8192;
    const __bf16* Bs_ = As_ + 4096;

    bf16x8 af[4], bfr[4];
#pragma unroll
    for (int tt = 0; tt < 4; ++tt) {
      af[tt]  = *(const bf16x8*)&As_[(wm * 64 + tt * 16 + l16) * 32 + cswz * 8];
      bfr[tt] = *(const bf16x8*)&Bs_[(wn * 64 + tt * 16 + l16) * 32 + cswz * 8];
    }
    __builtin_amdgcn_s_setprio(1);
#pragma unroll
    for (int mt = 0; mt < 4; ++mt)
#pragma unroll
      for (int nt = 0; nt < 4; ++nt)
        acc[mt][nt] = __builtin_amdgcn_mfma_f32_16x16x32_bf16(af[mt], bfr[nt], acc[mt][nt], 0, 0, 0);
    __builtin_amdgcn_s_setprio(0);

    if ((s & 31) == 31) {
      // epilogue for tile s>>5 (overlaps next tile's in-flight prefetch)
      const int t  = bx + ((s >> 5) << 9);
      const int m0 = DECODE_M(t);
      const int n0 = DECODE_N(t);
      // C/D layout: col = lane&15, row = quad*4 + reg
#pragma unroll
      for (int mt = 0; mt < 4; ++mt) {
#pragma unroll
        for (int nt = 0; nt < 4; ++nt) {
          const int n_idx = n0 + wn * 64 + nt * 16 + l16;
          const int mbase = m0 + wm * 64 + mt * 16 + quad * 4;
          if (EPI == 1) {
            if (out_bf16) {
#pragma unroll
              for (int r = 0; r < 4; ++r)
                ((__bf16*)Cout)[(size_t)(mbase + r) * N + n_idx] = (__bf16)acc[mt][nt][r];
            } else {
#pragma unroll
              for (int r = 0; r < 4; ++r)
                ((float*)Cout)[(size_t)(mbase + r) * N + n_idx] = acc[mt][nt][r];
            }
          } else {
            const int sel = n_idx >> 10;        // 0=Q 1=K 2=V (uniform per block)
            const int rem = n_idx & 1023;
            const int h   = rem >> 6;
            const int dh  = rem & 63;
            const int b   = mbase >> 11;        // same for r=0..3
            const int l   = mbase & 2047;
            const int bh  = b * 16 + h;
            if (sel == 2) {
              bf16x4 pk;
#pragma unroll
              for (int r = 0; r < 4; ++r) pk[r] = (__bf16)acc[mt][nt][r];
              *(bf16x4*)&vtb[((size_t)bh * 64 + dh) * 2048 + l] = pk;
            } else {
              __bf16* dstb = (sel == 0 ? qb : kb) + ((size_t)bh * 2048 + l) * 64 + dh;
#pragma unroll
              for (int r = 0; r < 4; ++r)
                dstb[(size_t)r * 64] = (__bf16)acc[mt][nt][r];
            }
          }
          acc[mt][nt] = (floatx4){0.f, 0.f, 0.f, 0.f};
        }
      }
    }
  }
}

// ---------------------------------------------------------------------------
// Flash attention: grid (L/128, B*H), 4 waves/block, 32 Q rows per wave.
// Fixed-shift softmax p = exp(s/8 - 8); l via ones-column (register B-frag).
// S^T = K Q^T with 16x16x32 MFMA; P goes through a small LDS round-trip to
// re-shape into the x32 PV A-fragment. The P scratch lives in the NEXT K/V
// staging buffer (dead during compute): wave w's P quarter == wave w's
// staging region, so P-write -> P-read -> stage-write are wave-private and
// one __syncthreads per K-tile suffices. K/V double-buffered via register
// prefetch issued before compute, written after (global latency hidden).
// ---------------------------------------------------------------------------
__launch_bounds__(256, 4)
__global__ void attn_kernel(const __bf16* __restrict__ qb,
                            const __bf16* __restrict__ kb,
                            const __bf16* __restrict__ vtb,
                            __bf16* __restrict__ ob /* [B,L,D] bf16 */)
{
  // [buf][ K(64 rows x 72) | V^T(64 rows x 72) ] ; quarter w (2304 elems) is
  // wave w's staging region AND its P scratch in the non-current buffer.
  __shared__ __align__(16) __bf16 S[2][2 * 64 * 72];

  const int tid  = threadIdx.x;
  const int wave = tid >> 6;
  const int lane = tid & 63;
  const int quad = lane >> 4;
  const int l16  = lane & 15;

  const int bh = blockIdx.y;
  const int b  = bh >> 4;
  const int h  = bh & 15;
  const int q0 = blockIdx.x * 128;

  const __bf16* Qp = qb  + (size_t)bh * 2048 * 64;
  const __bf16* Kp = kb  + (size_t)bh * 2048 * 64;
  const __bf16* Vp = vtb + (size_t)bh * 64 * 2048;

  const float C1 = 0.125f * 1.44269504f;
  const float C2 = -8.0f  * 1.44269504f;

  bf16x8 aq[2][2];
#pragma unroll
  for (int rt = 0; rt < 2; ++rt) {
    const __bf16* qrow = Qp + (size_t)(q0 + wave * 32 + rt * 16 + l16) * 64;
    aq[rt][0] = *(const bf16x8*)(qrow + quad * 8);
    aq[rt][1] = *(const bf16x8*)(qrow + 32 + quad * 8);
  }

  // ones column, x32 B-frag: B[k=quad*8+e][n=l16] = 1 at n==0
  bf16x8 onesb;
  {
    const __bf16 ov = (l16 == 0) ? (__bf16)1.0f : (__bf16)0.0f;
#pragma unroll
    for (int i = 0; i < 8; ++i) onesb[i] = ov;
  }

  floatx4 o[2][4], o5[2];
#pragma unroll
  for (int rt = 0; rt < 2; ++rt) {
    o5[rt] = (floatx4){0.f, 0.f, 0.f, 0.f};
#pragma unroll
    for (int dt = 0; dt < 4; ++dt) o[rt][dt] = (floatx4){0.f, 0.f, 0.f, 0.f};
  }

  // staging geometry: wave>>1 selects K(0)/V(1); wave&1 selects 32-row half.
  // per lane: 4 b128 chunks, row = srb + (lane>>3) + 8*i, col = (lane&7)*8.
  const int sarr = wave >> 1;
  const int srb  = (wave & 1) * 32;
  const int sr0  = lane >> 3;
  const int scol = (lane & 7) * 8;

  // prologue: stage tile 0 into S[0] (each wave its own quarter)
  {
    __bf16* dst = &S[0][sarr * (64 * 72)];
    if (sarr == 0) {
#pragma unroll
      for (int i = 0; i < 4; ++i) {
        const int row = srb + sr0 + 8 * i;
        *(bf16x8*)&dst[row * 72 + scol] = *(const bf16x8*)(Kp + (size_t)row * 64 + scol);
      }
    } else {
#pragma unroll
      for (int i = 0; i < 4; ++i) {
        const int row = srb + sr0 + 8 * i;
        *(bf16x8*)&dst[row * 72 + scol] = *(const bf16x8*)(Vp + (size_t)row * 2048 + scol);
      }
    }
  }
  __syncthreads();

  for (int kt = 0; kt < 32; ++kt) {
    const int cur = kt & 1;
    const int nxt = cur ^ 1;
    const int kn  = (((kt + 1) & 31) << 6);

    // issue next tile's global loads now; LDS-written after compute
    bf16x8 sreg[4];
    if (sarr == 0) {
#pragma unroll
      for (int i = 0; i < 4; ++i) {
        const int row = srb + sr0 + 8 * i;
        sreg[i] = *(const bf16x8*)(Kp + (size_t)(kn + row) * 64 + scol);
      }
    } else {
#pragma unroll
      for (int i = 0; i < 4; ++i) {
        const int row = srb + sr0 + 8 * i;
        sreg[i] = *(const bf16x8*)(Vp + (size_t)row * 2048 + kn + scol);
      }
    }

    const __bf16* Kc = &S[cur][0];
    const __bf16* Vc = &S[cur][64 * 72];
    __bf16*       Pq = &S[nxt][0] + wave * 2304;   // own quarter, 32 rows x 72

    // S^T = K Q^T (row=key, col=q): A=K-frags, B=Q-frags
    floatx4 st[2][4];
    __builtin_amdgcn_s_setprio(1);
#pragma unroll
    for (int nt = 0; nt < 4; ++nt) {
      const int krow = nt * 16 + l16;
      bf16x8 ak0 = *(const bf16x8*)&Kc[krow * 72 + quad * 8];
      bf16x8 ak1 = *(const bf16x8*)&Kc[krow * 72 + 32 + quad * 8];
#pragma unroll
      for (int rt = 0; rt < 2; ++rt) {
        floatx4 z = (floatx4){0.f, 0.f, 0.f, 0.f};
        z = __builtin_amdgcn_mfma_f32_16x16x32_bf16(ak0, aq[rt][0], z, 0, 0, 0);
        z = __builtin_amdgcn_mfma_f32_16x16x32_bf16(ak1, aq[rt][1], z, 0, 0, 0);
        st[rt][nt] = z;
      }
    }
    __builtin_amdgcn_s_setprio(0);

    // softmax + packed P write: lane holds keys nt*16+quad*4+{0..3} of q-row l16
#pragma unroll
    for (int rt = 0; rt < 2; ++rt) {
#pragma unroll
      for (int nt = 0; nt < 4; ++nt) {
        bf16x4 pk;
#pragma unroll
        for (int r = 0; r < 4; ++r)
          pk[r] = (__bf16)__builtin_amdgcn_exp2f(fmaf(st[rt][nt][r], C1, C2));
        *(bf16x4*)&Pq[(rt * 16 + l16) * 72 + nt * 16 + quad * 4] = pk;
      }
    }

    __builtin_amdgcn_wave_barrier();   // pin LDS write->read order (same wave)

    bf16x8 ap[2][2];
#pragma unroll
    for (int rt = 0; rt < 2; ++rt) {
      ap[rt][0] = *(const bf16x8*)&Pq[(rt * 16 + l16) * 72 + quad * 8];
      ap[rt][1] = *(const bf16x8*)&Pq[(rt * 16 + l16) * 72 + 32 + quad * 8];
    }

    __builtin_amdgcn_s_setprio(1);
#pragma unroll
    for (int dt = 0; dt < 4; ++dt) {
      const int vrow = dt * 16 + l16;
      bf16x8 bv0 = *(const bf16x8*)&Vc[vrow * 72 + quad * 8];
      bf16x8 bv1 = *(const bf16x8*)&Vc[vrow * 72 + 32 + quad * 8];
#pragma unroll
      for (int rt = 0; rt < 2; ++rt) {
        o[rt][dt] = __builtin_amdgcn_mfma_f32_16x16x32_bf16(ap[rt][0], bv0, o[rt][dt], 0, 0, 0);
        o[rt][dt] = __builtin_amdgcn_mfma_f32_16x16x32_bf16(ap[rt][1], bv1, o[rt][dt], 0, 0, 0);
      }
    }
    // ones-column: l accumulates in col 0 of o5
#pragma unroll
    for (int rt = 0; rt < 2; ++rt) {
      o5[rt] = __builtin_amdgcn_mfma_f32_16x16x32_bf16(ap[rt][0], onesb, o5[rt], 0, 0, 0);
      o5[rt] = __builtin_amdgcn_mfma_f32_16x16x32_bf16(ap[rt][1], onesb, o5[rt], 0, 0, 0);
    }
    __builtin_amdgcn_s_setprio(0);

    __builtin_amdgcn_wave_barrier();   // pin: stage writes stay below P reads (WAR, same quarter)

    // stage tile kt+1 into own quarter of S[nxt] (overwrites consumed P)
    {
      __bf16* dst = &S[nxt][sarr * (64 * 72)];
#pragma unroll
      for (int i = 0; i < 4; ++i) {
        const int row = srb + sr0 + 8 * i;
        *(bf16x8*)&dst[row * 72 + scol] = sreg[i];
      }
    }
    __syncthreads();   // next tile (and all P consumption) complete
  }

#pragma unroll
  for (int rt = 0; rt < 2; ++rt)
#pragma unroll
    for (int r = 0; r < 4; ++r) {
      const float lv  = row16_sum(l16 == 0 ? o5[rt][r] : 0.f);
      const float inv = 1.f / lv;
      const size_t rowbase =
          ((size_t)b * 2048 + q0 + wave * 32 + rt * 16 + quad * 4 + r) * 1024 + h * 64;
#pragma unroll
      for (int dt = 0; dt < 4; ++dt)
        ob[rowbase + dt * 16 + l16] = (__bf16)(o[rt][dt][r] * inv);
    }
}

// ---------------------------------------------------------------------------
extern "C" void kernel_launch(void* const* d_in, const int* in_sizes, int n_in,
                              void* d_out, int out_size, void* d_ws, size_t ws_size,
                              hipStream_t stream)
{
  (void)in_sizes; (void)n_in; (void)out_size; (void)ws_size;

  const void* x     = d_in[0];
  const void* wqkv  = d_in[1];
  const void* wproj = d_in[2];

  const size_t NX    = (size_t)8192 * 1024;
  const size_t NWQKV = (size_t)3072 * 1024;
  const size_t NWPRJ = (size_t)1024 * 1024;

  __bf16* qbuf   = (__bf16*)d_ws;
  __bf16* kbuf   = qbuf + NX;
  __bf16* vtbuf  = kbuf + NX;
  __bf16* abuf   = vtbuf + NX;
  __bf16* xb     = abuf + NX;
  __bf16* wqkvb  = xb + NX;
  __bf16* wprojb = wqkvb + NWQKV;

  dim3 blk(256);

  cvt3_kernel<<<dim3((NX + NWQKV + NWPRJ) / 2048), blk, 0, stream>>>(
      x, xb, NX / 8, wqkv, wqkvb, NWQKV / 8, wproj, wprojb);

  gemm_ptile_kernel<0><<<dim3(512), blk, 0, stream>>>(
      xb, wqkvb, nullptr, nullptr, qbuf, kbuf, vtbuf, 1536, 3072);

  attn_kernel<<<dim3(2048 / 128, 64), blk, 0, stream>>>(qbuf, kbuf, vtbuf, abuf);

  gemm_ptile_kernel<1><<<dim3(512), blk, 0, stream>>>(
      abuf, wprojb, wproj, d_out, nullptr, nullptr, nullptr, 512, 1024);
}